// Round 1
// 310.633 us; speedup vs baseline: 1.1376x; 1.1376x over previous
//
#include <hip/hip_runtime.h>

#define BB 32
#define SS 256
#define TT 256
#define HH 4096
#define EE 64

typedef unsigned int u32;
typedef float f4 __attribute__((ext_vector_type(4)));

// K1: per-block (b, s-chunk, h-chunk): reduce 32 s-rows into X[1024] (LDS),
// dot with W rows 0..63 restricted to the h-chunk, atomicAdd into cond.
// cond[b,e] = (1/S) * sum_h (sum_s x[b,s,h]) * W[e,h]
// x is streamed exactly once -> nontemporal loads keep L2 clean for W/pb/pd/limes.
__global__ __launch_bounds__(256) void k1_cond(const float* __restrict__ x,
                                               const float* __restrict__ W,
                                               float* __restrict__ cond) {
    __shared__ float X[1024];
    int id = blockIdx.x;
    int hc = id & 3;
    int sc = (id >> 2) & 7;
    int b  = id >> 5;
    int h0 = threadIdx.x * 4;
    int hb = hc * 1024;
    const float* src = x + ((size_t)b * SS + sc * 32) * HH + hb + h0;
    f4 acc = 0.f;
#pragma unroll 8
    for (int s = 0; s < 32; ++s) {
        f4 v = __builtin_nontemporal_load((const f4*)(src + (size_t)s * HH));
        acc += v;
    }
    *(f4*)(X + h0) = acc;
    __syncthreads();
    int wave = threadIdx.x >> 6, lane = threadIdx.x & 63;
    for (int e = wave; e < EE; e += 4) {
        const float* wrow = W + (size_t)e * HH + hb;
        float s = 0.f;
#pragma unroll
        for (int i = 0; i < 4; ++i) {
            int h = i * 256 + lane * 4;
            f4 wv = *(const f4*)(wrow + h);
            f4 xv = *(const f4*)(X + h);
            f4 p = wv * xv;
            s += p.x + p.y + p.z + p.w;
        }
#pragma unroll
        for (int off = 32; off; off >>= 1) s += __shfl_xor(s, off);
        if (lane == 0) atomicAdd(cond + b * EE + e, s * (1.0f / SS));
    }
}

// K3: scales (as before) + precompute pbd = pb+pd (T x H) and gshr = g*shr
// in otherwise-idle blocks (fuse=1 iff workspace is big enough).
__global__ __launch_bounds__(256) void k3_prep(const float* __restrict__ pb,
                                               const float* __restrict__ pd,
                                               const float* __restrict__ shr,
                                               const float* __restrict__ gamma,
                                               const float* __restrict__ cond,
                                               u32* __restrict__ scaleBits,
                                               float* __restrict__ pbd,
                                               float* __restrict__ gshr,
                                               int fuse) {
    int bid = blockIdx.x;
    if (fuse) {
        if (bid < TT) {  // pbd row
            size_t rb = (size_t)bid * HH;
            const f4* a = (const f4*)(pb + rb);
            const f4* c = (const f4*)(pd + rb);
            f4* o = (f4*)(pbd + rb);
#pragma unroll
            for (int i = 0; i < 4; ++i) {
                int j = i * 256 + threadIdx.x;
                o[j] = a[j] + c[j];
            }
            return;
        }
        if (bid < TT + 4) {  // gshr
            int j = (bid - TT) * 256 + threadIdx.x;
            float g = 1.f / (1.f + __expf(-gamma[0]));
            ((f4*)gshr)[j] = g * ((const f4*)shr)[j];
            return;
        }
    }
    int sb = fuse ? (TT + 4) : 0;
    int tid = (bid - sb) * 256 + threadIdx.x;  // 32768 threads
    float hmax = 0.f, dmax = 0.f;
    for (int idx = tid; idx < BB * TT * EE; idx += 32768) {
        int e = idx & 63, t = (idx >> 6) & 255, b = idx >> 14;
        float v = pb[t * HH + e] + cond[b * EE + e];
        hmax = fmaxf(hmax, fabsf(v));
    }
    for (int idx = tid; idx < TT * EE; idx += 32768) {
        int e = idx & 63, t = idx >> 6;
        dmax = fmaxf(dmax, fabsf(pd[t * HH + e]));
    }
#pragma unroll
    for (int off = 32; off; off >>= 1) {
        hmax = fmaxf(hmax, __shfl_xor(hmax, off));
        dmax = fmaxf(dmax, __shfl_xor(dmax, off));
    }
    __shared__ float sh[4], sd[4];
    int wave = threadIdx.x >> 6, lane = threadIdx.x & 63;
    if (lane == 0) { sh[wave] = hmax; sd[wave] = dmax; }
    __syncthreads();
    if (threadIdx.x == 0) {
        float h = sh[0], d = sd[0];
#pragma unroll
        for (int i = 1; i < 4; ++i) { h = fmaxf(h, sh[i]); d = fmaxf(d, sd[i]); }
        atomicMax(scaleBits + 0, __float_as_uint(h));
        atomicMax(scaleBits + 1, __float_as_uint(d));
    }
}

// K4: one wave per (b,t) row. launch_bounds(256,4): 128-VGPR budget so the
// fully-unrolled stream loop can keep multiple iterations of loads in flight
// (at 48 VGPRs the loop was latency-serialized: ~1575 cyc/iter measured).
// Nontemporal stores keep the 132MB write stream from evicting the read set.
template<int FUSE>
__global__ __launch_bounds__(256, 4) void k4_main(const float* __restrict__ pb,
                                                  const float* __restrict__ pd,
                                                  const float* __restrict__ limes,
                                                  const float* __restrict__ shr,
                                                  const float* __restrict__ gamma,
                                                  const float* __restrict__ cond,
                                                  const u32* __restrict__ scaleBits,
                                                  const float* __restrict__ pbd,
                                                  const float* __restrict__ gshr,
                                                  float* __restrict__ out) {
    int wave = threadIdx.x >> 6, lane = threadIdx.x & 63;
    int row = blockIdx.x * 4 + wave;  // 0..8191
    int b = row >> 8, t = row & 255;

    float Hs = fmaxf(__uint_as_float(scaleBits[0]), 1e-6f);
    float Ds = fmaxf(__uint_as_float(scaleBits[1]), 1e-6f);
    float g = 1.f / (1.f + __expf(-gamma[0]));

    size_t rb = (size_t)t * HH;
    float logit = 0.5f * (pb[rb + lane] + cond[b * EE + lane]) / Hs
                + 0.5f * pd[rb + lane] / Ds;

    int selIdx[4]; float selL[4];
    float work = logit;
#pragma unroll
    for (int k = 0; k < 4; ++k) {
        float v = work; int vi = lane;
#pragma unroll
        for (int off = 32; off; off >>= 1) {
            float ov = __shfl_xor(v, off);
            int   oi = __shfl_xor(vi, off);
            if (ov > v || (ov == v && oi < vi)) { v = ov; vi = oi; }
        }
        selIdx[k] = vi; selL[k] = v;
        if (lane == vi) work = -1e30f;
    }
    float m = selL[0];
    float w0 = __expf(selL[0] - m), w1 = __expf(selL[1] - m);
    float w2 = __expf(selL[2] - m), w3 = __expf(selL[3] - m);
    float inv = 1.f / (w0 + w1 + w2 + w3);
    w0 *= inv; w1 *= inv; w2 *= inv; w3 *= inv;

    const float* L0 = limes + (size_t)selIdx[0] * HH;
    const float* L1 = limes + (size_t)selIdx[1] * HH;
    const float* L2 = limes + (size_t)selIdx[2] * HH;
    const float* L3 = limes + (size_t)selIdx[3] * HH;
    size_t ob = (size_t)row * HH;
    float om = 1.f - g;

    if (FUSE) {
        // out = pbd * (sum_k (om*w_k)*L_k + g*shr): 6 streams, 5 fma/elem
        float c0 = w0 * om, c1 = w1 * om, c2 = w2 * om, c3 = w3 * om;
        const float* P = pbd + rb;
#pragma unroll
        for (int i = 0; i < 16; ++i) {
            int h = i * 256 + lane * 4;
            f4 fp = *(const f4*)(P + h);
            f4 f0 = *(const f4*)(L0 + h);
            f4 f1 = *(const f4*)(L1 + h);
            f4 f2 = *(const f4*)(L2 + h);
            f4 f3 = *(const f4*)(L3 + h);
            f4 fg = *(const f4*)(gshr + h);
            f4 mix = fg + c0 * f0 + c1 * f1 + c2 * f2 + c3 * f3;
            f4 r = fp * mix;
            __builtin_nontemporal_store(r, (f4*)(out + ob + h));
        }
    } else {
#pragma unroll
        for (int i = 0; i < 16; ++i) {
            int h = i * 256 + lane * 4;
            f4 fb = *(const f4*)(pb + rb + h);
            f4 fd = *(const f4*)(pd + rb + h);
            f4 f0 = *(const f4*)(L0 + h);
            f4 f1 = *(const f4*)(L1 + h);
            f4 f2 = *(const f4*)(L2 + h);
            f4 f3 = *(const f4*)(L3 + h);
            f4 fs = *(const f4*)(shr + h);
            f4 pm = w0 * f0 + w1 * f1 + w2 * f2 + w3 * f3;
            f4 r = (fb + fd) * (om * pm + g * fs);
            __builtin_nontemporal_store(r, (f4*)(out + ob + h));
        }
    }
}

extern "C" void kernel_launch(void* const* d_in, const int* in_sizes, int n_in,
                              void* d_out, int out_size, void* d_ws, size_t ws_size,
                              hipStream_t stream) {
    // Pointers by size (proven equivalent to dict order in R2/R3 A/B).
    const float *x = 0, *pb = 0, *pd = 0, *limes = 0, *shr = 0, *gm = 0, *W = 0;
    for (int i = 0; i < n_in; ++i) {
        const float* p = (const float*)d_in[i];
        switch (in_sizes[i]) {
            case BB * SS * HH: x = p; break;
            case TT * HH: if (!pb) pb = p; else pd = p; break;
            case EE * HH: limes = p; break;
            case HH: shr = p; break;
            case 1: gm = p; break;
            case HH * HH: W = p; break;
        }
    }
    float* out = (float*)d_out;  // reference output dtype = float32

    // ws: [0..1]=scaleBits, [2..]=cond (B*E f32), then gshr (H), pbd (T*H)
    u32* scaleBits = (u32*)d_ws;
    float* cond = (float*)d_ws + 2;
    float* gshr = (float*)d_ws + 2 + BB * EE;
    float* pbd  = gshr + HH;
    size_t need = (size_t)(2 + BB * EE + HH) * sizeof(float)
                + (size_t)TT * HH * sizeof(float);
    int fuse = (ws_size >= need) ? 1 : 0;

    hipMemsetAsync(d_ws, 0, (2 + BB * EE) * sizeof(float), stream);
    k1_cond<<<BB * 8 * 4, 256, 0, stream>>>(x, W, cond);
    k3_prep<<<fuse ? (TT + 4 + 128) : 128, 256, 0, stream>>>(pb, pd, shr, gm, cond,
                                                             scaleBits, pbd, gshr, fuse);
    if (fuse)
        k4_main<1><<<BB * TT / 4, 256, 0, stream>>>(pb, pd, limes, shr, gm, cond,
                                                    scaleBits, pbd, gshr, out);
    else
        k4_main<0><<<BB * TT / 4, 256, 0, stream>>>(pb, pd, limes, shr, gm, cond,
                                                    scaleBits, pbd, gshr, out);
}

// Round 4
// 310.148 us; speedup vs baseline: 1.1394x; 1.0016x over previous
//
#include <hip/hip_runtime.h>

#define BB 32
#define SS 256
#define TT 256
#define HH 4096
#define EE 64

typedef unsigned int u32;
typedef float f4 __attribute__((ext_vector_type(4)));

// K1: per-block (b, s-chunk, h-chunk): reduce 32 s-rows into X[1024] (LDS),
// dot with W rows 0..63 restricted to the h-chunk, atomicAdd into cond.
// cond[b,e] = (1/S) * sum_h (sum_s x[b,s,h]) * W[e,h]
// launch_bounds(256,4): 128-VGPR budget so the load stream stays in flight
// (same fix that unblocked k4 in R1). unroll 8 = the exact R1-green form.
__global__ __launch_bounds__(256, 4) void k1_cond(const float* __restrict__ x,
                                                  const float* __restrict__ W,
                                                  float* __restrict__ cond) {
    __shared__ float X[1024];
    int id = blockIdx.x;
    int hc = id & 3;
    int sc = (id >> 2) & 7;
    int b  = id >> 5;
    int h0 = threadIdx.x * 4;
    int hb = hc * 1024;
    const float* src = x + ((size_t)b * SS + sc * 32) * HH + hb + h0;
    f4 acc = 0.f;
#pragma unroll 8
    for (int s = 0; s < 32; ++s) {
        f4 v = __builtin_nontemporal_load((const f4*)(src + (size_t)s * HH));
        acc += v;
    }
    *(f4*)(X + h0) = acc;
    __syncthreads();
    int wave = threadIdx.x >> 6, lane = threadIdx.x & 63;
    for (int e = wave; e < EE; e += 4) {
        const float* wrow = W + (size_t)e * HH + hb;
        float s = 0.f;
#pragma unroll
        for (int i = 0; i < 4; ++i) {
            int h = i * 256 + lane * 4;
            f4 wv = *(const f4*)(wrow + h);
            f4 xv = *(const f4*)(X + h);
            f4 p = wv * xv;
            s += p.x + p.y + p.z + p.w;
        }
#pragma unroll
        for (int off = 32; off; off >>= 1) s += __shfl_xor(s, off);
        if (lane == 0) atomicAdd(cond + b * EE + e, s * (1.0f / SS));
    }
}

// K3: scales only (pbd/gshr precompute moved into k4's LDS staging).
__global__ __launch_bounds__(256) void k3_scales(const float* __restrict__ pb,
                                                 const float* __restrict__ pd,
                                                 const float* __restrict__ cond,
                                                 u32* __restrict__ scaleBits) {
    int tid = blockIdx.x * 256 + threadIdx.x;  // 32768 threads
    float hmax = 0.f, dmax = 0.f;
    for (int idx = tid; idx < BB * TT * EE; idx += 32768) {
        int e = idx & 63, t = (idx >> 6) & 255, b = idx >> 14;
        float v = pb[t * HH + e] + cond[b * EE + e];
        hmax = fmaxf(hmax, fabsf(v));
    }
    for (int idx = tid; idx < TT * EE; idx += 32768) {
        int e = idx & 63, t = idx >> 6;
        dmax = fmaxf(dmax, fabsf(pd[t * HH + e]));
    }
#pragma unroll
    for (int off = 32; off; off >>= 1) {
        hmax = fmaxf(hmax, __shfl_xor(hmax, off));
        dmax = fmaxf(dmax, __shfl_xor(dmax, off));
    }
    __shared__ float sh[4], sd[4];
    int wave = threadIdx.x >> 6, lane = threadIdx.x & 63;
    if (lane == 0) { sh[wave] = hmax; sd[wave] = dmax; }
    __syncthreads();
    if (threadIdx.x == 0) {
        float h = sh[0], d = sd[0];
#pragma unroll
        for (int i = 1; i < 4; ++i) { h = fmaxf(h, sh[i]); d = fmaxf(d, sd[i]); }
        atomicMax(scaleBits + 0, __float_as_uint(h));
        atomicMax(scaleBits + 1, __float_as_uint(d));
    }
}

// K4: block = (t, bq); the 4 waves share t (b = bq*4+wave). pb[t]+pd[t] and
// g*shr are staged once per block into LDS, so the stream loop's vector-memory
// reads drop from 6 global streams to 4 (limes rows only) + 2 DS reads.
// DS pipe is separate from the VMEM pipe -> cuts the limiting read traffic.
// LDS 32KB/block x 4 blocks/CU = 128KB <= 160KB.
__global__ __launch_bounds__(256, 4) void k4_main(const float* __restrict__ pb,
                                                  const float* __restrict__ pd,
                                                  const float* __restrict__ limes,
                                                  const float* __restrict__ shr,
                                                  const float* __restrict__ gamma,
                                                  const float* __restrict__ cond,
                                                  const u32* __restrict__ scaleBits,
                                                  float* __restrict__ out) {
    __shared__ float Pbd[HH];  // pb[t]+pd[t], 16 KB
    __shared__ float Gs[HH];   // g*shr,      16 KB
    int t  = blockIdx.x >> 3;
    int bq = blockIdx.x & 7;
    float g = 1.f / (1.f + __expf(-gamma[0]));
    size_t rb = (size_t)t * HH;

    {   // cooperative stage: 4 f4 per thread per array
        const f4* Pb = (const f4*)(pb + rb);
        const f4* Pd = (const f4*)(pd + rb);
        const f4* Sh = (const f4*)shr;
#pragma unroll
        for (int i = 0; i < 4; ++i) {
            int j = i * 256 + threadIdx.x;
            f4 a = Pb[j];
            f4 c = Pd[j];
            f4 s = Sh[j];
            ((f4*)Pbd)[j] = a + c;
            ((f4*)Gs)[j]  = g * s;
        }
    }
    __syncthreads();

    int wave = threadIdx.x >> 6, lane = threadIdx.x & 63;
    int b = bq * 4 + wave;

    float Hs = fmaxf(__uint_as_float(scaleBits[0]), 1e-6f);
    float Ds = fmaxf(__uint_as_float(scaleBits[1]), 1e-6f);

    float logit = 0.5f * (pb[rb + lane] + cond[b * EE + lane]) / Hs
                + 0.5f * pd[rb + lane] / Ds;

    int selIdx[4]; float selL[4];
    float work = logit;
#pragma unroll
    for (int k = 0; k < 4; ++k) {
        float v = work; int vi = lane;
#pragma unroll
        for (int off = 32; off; off >>= 1) {
            float ov = __shfl_xor(v, off);
            int   oi = __shfl_xor(vi, off);
            if (ov > v || (ov == v && oi < vi)) { v = ov; vi = oi; }
        }
        selIdx[k] = vi; selL[k] = v;
        if (lane == vi) work = -1e30f;
    }
    float m = selL[0];
    float w0 = __expf(selL[0] - m), w1 = __expf(selL[1] - m);
    float w2 = __expf(selL[2] - m), w3 = __expf(selL[3] - m);
    float inv = 1.f / (w0 + w1 + w2 + w3);
    float om = 1.f - g;
    float c0 = w0 * inv * om, c1 = w1 * inv * om;
    float c2 = w2 * inv * om, c3 = w3 * inv * om;

    const float* L0 = limes + (size_t)selIdx[0] * HH;
    const float* L1 = limes + (size_t)selIdx[1] * HH;
    const float* L2 = limes + (size_t)selIdx[2] * HH;
    const float* L3 = limes + (size_t)selIdx[3] * HH;
    size_t ob = ((size_t)b * TT + t) * HH;

#pragma unroll
    for (int i = 0; i < 16; ++i) {
        int h = i * 256 + lane * 4;
        f4 fp = *(const f4*)(Pbd + h);
        f4 fg = *(const f4*)(Gs + h);
        f4 f0 = *(const f4*)(L0 + h);
        f4 f1 = *(const f4*)(L1 + h);
        f4 f2 = *(const f4*)(L2 + h);
        f4 f3 = *(const f4*)(L3 + h);
        f4 mix = fg + c0 * f0 + c1 * f1 + c2 * f2 + c3 * f3;
        f4 r = fp * mix;
        __builtin_nontemporal_store(r, (f4*)(out + ob + h));
    }
}

extern "C" void kernel_launch(void* const* d_in, const int* in_sizes, int n_in,
                              void* d_out, int out_size, void* d_ws, size_t ws_size,
                              hipStream_t stream) {
    // Pointers by size (proven equivalent to dict order in R2/R3 A/B).
    const float *x = 0, *pb = 0, *pd = 0, *limes = 0, *shr = 0, *gm = 0, *W = 0;
    for (int i = 0; i < n_in; ++i) {
        const float* p = (const float*)d_in[i];
        switch (in_sizes[i]) {
            case BB * SS * HH: x = p; break;
            case TT * HH: if (!pb) pb = p; else pd = p; break;
            case EE * HH: limes = p; break;
            case HH: shr = p; break;
            case 1: gm = p; break;
            case HH * HH: W = p; break;
        }
    }
    float* out = (float*)d_out;  // reference output dtype = float32

    // ws: [0..1]=scaleBits, [2..]=cond (B*E f32)
    u32* scaleBits = (u32*)d_ws;
    float* cond = (float*)d_ws + 2;

    hipMemsetAsync(d_ws, 0, (2 + BB * EE) * sizeof(float), stream);
    k1_cond<<<BB * 8 * 4, 256, 0, stream>>>(x, W, cond);
    k3_scales<<<128, 256, 0, stream>>>(pb, pd, cond, scaleBits);
    k4_main<<<BB * TT / 4, 256, 0, stream>>>(pb, pd, limes, shr, gm, cond,
                                             scaleBits, out);
}